// Round 3
// baseline (3342.941 us; speedup 1.0000x reference)
//
#include <hip/hip_runtime.h>

typedef _Float16 f16;
typedef __attribute__((ext_vector_type(4))) _Float16 f16x4;
typedef __attribute__((ext_vector_type(8))) _Float16 f16x8;
typedef __attribute__((ext_vector_type(4))) float f32x4;

#define NB   512
#define NI   128
#define NH   1024
#define NG   4096
#define NSEQ 96

__device__ __forceinline__ float sigm(float x)  { return 1.0f / (1.0f + __expf(-x)); }
__device__ __forceinline__ float tanhf_(float x){ return 2.0f / (1.0f + __expf(-2.0f * x)) - 1.0f; }

// R13: fence-free persistent kernel. R12 evidence: FETCH_SIZE 589MB/dispatch
// (6.2MB/step) at 338GB/s, MfmaUtil 5.6% -> __threadfence's buffer_inv/wbl2
// flushed L2 every step; h+c refetched from HBM with 4 waves/CU of hiding.
// Fix: only h is cross-block. h accesses -> relaxed AGENT atomics (sc0 sc1:
// write-through to LIC / L1-L2-bypassing loads). c stays warm+dirty in L2 all
// 95 steps. Barrier: __syncthreads drains vmcnt (stores then at coherence
// point) -> relaxed atomicAdd + relaxed spin (s_sleep), per-rt-group (64
// blocks, 4 counters). out via R10 fold on strip-0 blocks (no atomics).

__device__ __forceinline__ uint32_t cload(const uint32_t* p) {
    return __hip_atomic_load((uint32_t*)p, __ATOMIC_RELAXED, __HIP_MEMORY_SCOPE_AGENT);
}
__device__ __forceinline__ void cstore(uint32_t* p, uint32_t v) {
    __hip_atomic_store(p, v, __ATOMIC_RELAXED, __HIP_MEMORY_SCOPE_AGENT);
}

union U4 { uint32_t u[4]; f16x8 v; };

__global__ __launch_bounds__(256)
void prep1_kernel(const float* __restrict__ xt, const float* __restrict__ hidden,
                  const float* __restrict__ W_ih, const float* __restrict__ b_ih,
                  const float* __restrict__ b_hh, const float* __restrict__ b_fc,
                  f16* __restrict__ wih, f16* __restrict__ xbuf,
                  f16* __restrict__ h0, float* __restrict__ bias_eff,
                  unsigned* __restrict__ bar)
{
    const int gid = blockIdx.x * 256 + threadIdx.x;
    const int GSZ = 256 * 256;
    if (gid < 128) bar[gid] = 0u;         // 4 group counters (128B-spaced), re-zeroed every launch
    { const float4* s = (const float4*)W_ih; f16x4* d = (f16x4*)wih;
      for (int i = gid; i < NG * NI / 4; i += GSZ) { float4 v = s[i]; d[i] = f16x4{(f16)v.x,(f16)v.y,(f16)v.z,(f16)v.w}; } }
    { const float4* s = (const float4*)xt; f16x4* d = (f16x4*)xbuf;
      for (int i = gid; i < NB * NI / 4; i += GSZ) { float4 v = s[i]; d[i] = f16x4{(f16)v.x,(f16)v.y,(f16)v.z,(f16)v.w}; } }
    { const float4* s = (const float4*)hidden; f16x4* d = (f16x4*)h0;
      for (int i = gid; i < NB * NH / 4; i += GSZ) { float4 v = s[i]; d[i] = f16x4{(f16)v.x,(f16)v.y,(f16)v.z,(f16)v.w}; } }
    if (gid < NG) {                       // bias_eff[n] = b_ih+b_hh + W_ih[n,:].b_fc
        float s = b_ih[gid] + b_hh[gid];
        const float* wr = W_ih + gid * NI;
        for (int j = 0; j < NI; ++j) s += wr[j] * b_fc[j];
        bias_eff[gid] = s;
    }
}

// W_eff = W_hh + W_ih @ W_fc  -> fp16.  512 blocks: (nt=bid>>3)x(kt=bid&7),
// tile = 64 gate-rows x 128 k-cols, K=128.
__global__ __launch_bounds__(256)
void prep2_kernel(const f16* __restrict__ wih, const float* __restrict__ W_fc,
                  const float* __restrict__ W_hh, f16* __restrict__ weff)
{
    __shared__ f16 ldsW[64 * 136];        // A tile 64x128 fp16, pitch 136

    const int tid = threadIdx.x;
    const int nt = blockIdx.x >> 3, kt = blockIdx.x & 7;
    const int w = tid >> 6, lane = tid & 63, quad = lane >> 4, l16 = lane & 15;

    for (int s = 0; s < 4; ++s) {
        const int slot = tid + s * 256;            // 1024 vec8 slots
        const int row = slot >> 4, colv = slot & 15;
        *(f16x8*)(ldsW + row * 136 + colv * 8) =
            *(const f16x8*)(wih + (nt * 64 + row) * NI + colv * 8);
    }
    __syncthreads();

    f32x4 acc[4][2];
#pragma unroll
    for (int mt = 0; mt < 4; ++mt) { acc[mt][0] = f32x4{0,0,0,0}; acc[mt][1] = f32x4{0,0,0,0}; }

    const int nc0 = kt * 128 + w * 32;
#pragma unroll
    for (int c = 0; c < 4; ++c) {
        f16x8 bf0, bf1;
#pragma unroll
        for (int j = 0; j < 8; ++j) {
            const int krow = c * 32 + quad * 8 + j;
            bf0[j] = (f16)W_fc[krow * NH + nc0 + l16];
            bf1[j] = (f16)W_fc[krow * NH + nc0 + 16 + l16];
        }
#pragma unroll
        for (int mt = 0; mt < 4; ++mt) {
            f16x8 afr = *(const f16x8*)(ldsW + (mt * 16 + l16) * 136 + c * 32 + quad * 8);
            acc[mt][0] = __builtin_amdgcn_mfma_f32_16x16x32_f16(afr, bf0, acc[mt][0], 0, 0, 0);
            acc[mt][1] = __builtin_amdgcn_mfma_f32_16x16x32_f16(afr, bf1, acc[mt][1], 0, 0, 0);
        }
    }

#pragma unroll
    for (int mt = 0; mt < 4; ++mt)
#pragma unroll
        for (int r = 0; r < 4; ++r) {
            const int n = nt * 64 + mt * 16 + quad * 4 + r;
            weff[n * NH + nc0 + l16]      = (f16)(acc[mt][0][r] + W_hh[n * NH + nc0 + l16]);
            weff[n * NH + nc0 + 16 + l16] = (f16)(acc[mt][1][r] + W_hh[n * NH + nc0 + 16 + l16]);
        }
}

// t=0: gates = x0@W_ih^T + h0@W_hh^T + (b_ih+b_hh); K=1152. W_hh read f32.
__global__ __launch_bounds__(256)
void step0_kernel(const f16* __restrict__ xbuf, const f16* __restrict__ hin,
                  f16* __restrict__ hout, const f16* __restrict__ wih,
                  const float* __restrict__ W_hh, const float* __restrict__ b_ih,
                  const float* __restrict__ b_hh, float* __restrict__ cglob)
{
    __shared__ f16   ldsA[2 * 64 * 40];
    __shared__ float gbuf[4][64][33];

    const int tid = threadIdx.x, bid = blockIdx.x;
    const int r0 = (bid >> 5) * 64, u0 = (bid & 31) * 32;
    const int w = tid >> 6, lane = tid & 63, quad = lane >> 4, l16 = lane & 15;
    const int srow = tid >> 2, skk = (tid & 3) * 8;

    const int n0g = w * NH + u0 + l16;
    const f16*   wip0 = wih + n0g * NI + quad * 8;
    const f16*   wip1 = wip0 + 16 * NI;
    const float* whf0 = W_hh + n0g * NH + quad * 8;
    const float* whf1 = whf0 + 16 * NH;
    const float bias0 = b_ih[n0g]      + b_hh[n0g];
    const float bias1 = b_ih[n0g + 16] + b_hh[n0g + 16];

    const f16* xrow = xbuf + (r0 + srow) * NI + skk;
    const f16* hrow = hin  + (r0 + srow) * NH + skk;

    f32x4 acc[4][2];
#pragma unroll
    for (int mt = 0; mt < 4; ++mt) { acc[mt][0] = f32x4{0,0,0,0}; acc[mt][1] = f32x4{0,0,0,0}; }

    auto loadA = [&](int kb) -> f16x8 {
        const int k0 = kb * 32;
        if (k0 < NI) return *(const f16x8*)(xrow + k0);
        return *(const f16x8*)(hrow + (k0 - NI));
    };
    auto cvt8 = [&](const float* p) -> f16x8 {
        float4 a = *(const float4*)p, b = *(const float4*)(p + 4);
        return f16x8{(f16)a.x,(f16)a.y,(f16)a.z,(f16)a.w,(f16)b.x,(f16)b.y,(f16)b.z,(f16)b.w};
    };
    auto loadB0 = [&](int kb) -> f16x8 {
        const int k0 = kb * 32;
        if (k0 < NI) return *(const f16x8*)(wip0 + k0);
        return cvt8(whf0 + (k0 - NI));
    };
    auto loadB1 = [&](int kb) -> f16x8 {
        const int k0 = kb * 32;
        if (k0 < NI) return *(const f16x8*)(wip1 + k0);
        return cvt8(whf1 + (k0 - NI));
    };

    f16x8 av = loadA(0);
    *(f16x8*)(ldsA + srow * 40 + skk) = av;
    av = loadA(1);
    f16x8 b0 = loadB0(0), b1 = loadB1(0);

    for (int kb = 0; kb < 36; ++kb) {
        __syncthreads();
        if (kb + 1 < 36) {
            *(f16x8*)(ldsA + ((kb + 1) & 1) * 2560 + srow * 40 + skk) = av;
            av = loadA(kb + 2 < 36 ? kb + 2 : 35);
        }
        const int kn = (kb + 1 < 36) ? kb + 1 : 35;
        f16x8 nb0 = loadB0(kn), nb1 = loadB1(kn);
        const f16* abase = ldsA + (kb & 1) * 2560 + l16 * 40 + quad * 8;
#pragma unroll
        for (int mt = 0; mt < 4; ++mt) {
            f16x8 afr = *(const f16x8*)(abase + mt * 640);
            acc[mt][0] = __builtin_amdgcn_mfma_f32_16x16x32_f16(afr, b0, acc[mt][0], 0, 0, 0);
            acc[mt][1] = __builtin_amdgcn_mfma_f32_16x16x32_f16(afr, b1, acc[mt][1], 0, 0, 0);
        }
        b0 = nb0; b1 = nb1;
    }

#pragma unroll
    for (int mt = 0; mt < 4; ++mt)
#pragma unroll
        for (int r = 0; r < 4; ++r) {
            gbuf[w][mt * 16 + quad * 4 + r][l16]      = acc[mt][0][r] + bias0;
            gbuf[w][mt * 16 + quad * 4 + r][16 + l16] = acc[mt][1][r] + bias1;
        }
    __syncthreads();

    {
        const int uu = tid & 31, rbase = (tid >> 5) * 8;
#pragma unroll
        for (int s = 0; s < 8; ++s) {
            const int rr = rbase + s;
            const int gi = (r0 + rr) * NH + u0 + uu;
            const float iv = gbuf[0][rr][uu], fv = gbuf[1][rr][uu];
            const float gv = gbuf[2][rr][uu], ov = gbuf[3][rr][uu];
            const float cn = sigm(fv) * cglob[gi] + sigm(iv) * tanhf_(gv);
            cglob[gi] = cn;
            hout[gi]  = (f16)(sigm(ov) * tanhf_(cn));
        }
    }
}

// Persistent kernel: steps t=1..95.  256 blocks (1/CU) x 256 threads.
// block = (rt = bid>>6: 128-row tile) x (us = bid&63: 16-unit strip).
// LDS: W_eff strip in MFMA B-fragment order, 128 KiB, loaded once.
// h written via relaxed AGENT atomic dword stores (write-through to LIC),
// read via relaxed AGENT atomic dword loads (L1/L2 bypass). c/acc private.
// Per-rt-group relaxed barrier. Strip-0 blocks fold out[:,t-1] from A-frags.
__global__ __launch_bounds__(256, 1)
void lstm_persist(f16* h0, f16* h1,
                  const f16* __restrict__ weff, const float* __restrict__ bias_eff,
                  float* __restrict__ cglob, const float* __restrict__ wfc_last,
                  const float* __restrict__ b_fc, float* __restrict__ out,
                  unsigned* bar)
{
    __shared__ f16 ldsB[4 * 32 * 64 * 8];   // 128 KiB: frag[(g*32+kb)*64 + lane]

    const int tid = threadIdx.x, bid = blockIdx.x;
    const int rt = bid >> 6, us = bid & 63;
    const int u0 = us * 16;
    const int w = tid >> 6, lane = tid & 63, quad = lane >> 4, l16 = lane & 15;
    const bool stp0 = (us == 0);

    // ---- preload W strip into LDS in fragment order (wave w owns gate g=w) ----
    {
        const f16* src = weff + (w * NH + u0 + l16) * NH + quad * 8;
        f16x8* dst = ((f16x8*)ldsB) + (w * 32) * 64 + lane;
#pragma unroll
        for (int kb = 0; kb < 32; ++kb)
            dst[kb * 64] = *(const f16x8*)(src + kb * 32);
    }

    const float bi = bias_eff[0 * NH + u0 + l16];
    const float bf = bias_eff[1 * NH + u0 + l16];
    const float bg = bias_eff[2 * NH + u0 + l16];
    const float bo = bias_eff[3 * NH + u0 + l16];
    const float bfc127 = b_fc[127];

    const int rows0 = rt * 128 + w * 32;
    const int aoff0 = (rows0 + l16) * NH + quad * 8;        // f16 offset, 16B aligned
    const int aoff1 = aoff0 + 16 * NH;
    const int gbase = (rows0 + quad * 4) * NH + u0 + l16;   // + (i*16 + r)*NH

    unsigned* mybar = bar + rt * 32;        // 128B-spaced group counters
    const f16x8* lb = (const f16x8*)ldsB;

    int dead = 0;                           // barrier-timeout flag (thread 0 only)
    __syncthreads();                        // W strip ready

#pragma unroll 1
    for (int t = 1; t < NSEQ; ++t) {
        const f16* hin  = (t & 1) ? h1 : h0;
        f16*       hout = (t & 1) ? h0 : h1;

        // private cell values (written by this same thread last step; L2-warm)
        float cv0[4], cv1[4];
#pragma unroll
        for (int r = 0; r < 4; ++r) {
            cv0[r] = cglob[gbase + r * NH];
            cv1[r] = cglob[gbase + (16 + r) * NH];
        }

        const uint32_t* ap0 = (const uint32_t*)hin + (aoff0 >> 1);
        const uint32_t* ap1 = (const uint32_t*)hin + (aoff1 >> 1);

        U4 a0[4], a1[4];
#pragma unroll
        for (int s = 0; s < 4; ++s)
#pragma unroll
            for (int d = 0; d < 4; ++d) {
                a0[s].u[d] = cload(ap0 + s * 16 + d);
                a1[s].u[d] = cload(ap1 + s * 16 + d);
            }
        f16x8 b0 = lb[(0 * 32 + 0) * 64 + lane];
        f16x8 b1 = lb[(1 * 32 + 0) * 64 + lane];
        f16x8 b2 = lb[(2 * 32 + 0) * 64 + lane];
        f16x8 b3 = lb[(3 * 32 + 0) * 64 + lane];

        f32x4 acc[2][4];
#pragma unroll
        for (int i = 0; i < 2; ++i)
#pragma unroll
            for (int g = 0; g < 4; ++g) acc[i][g] = f32x4{0.f, 0.f, 0.f, 0.f};

        float dot0 = 0.f, dot1 = 0.f;       // strip-0 fold: out[:,t-1] = hin . wfc_last

#pragma unroll
        for (int kb = 0; kb < 32; ++kb) {
            const int kn = (kb + 1) & 31;                   // kb=31 reads frag 0 (discarded)
            f16x8 n0 = lb[(0 * 32 + kn) * 64 + lane];
            f16x8 n1 = lb[(1 * 32 + kn) * 64 + lane];
            f16x8 n2 = lb[(2 * 32 + kn) * 64 + lane];
            f16x8 n3 = lb[(3 * 32 + kn) * 64 + lane];
            const f16x8 fa0 = a0[kb & 3].v, fa1 = a1[kb & 3].v;
            if (stp0) {
                const float* wf = wfc_last + kb * 32 + quad * 8;
#pragma unroll
                for (int j = 0; j < 8; ++j) {
                    dot0 += (float)fa0[j] * wf[j];
                    dot1 += (float)fa1[j] * wf[j];
                }
            }
            if (kb + 4 < 32) {
#pragma unroll
                for (int d = 0; d < 4; ++d) {
                    a0[kb & 3].u[d] = cload(ap0 + (kb + 4) * 16 + d);
                    a1[kb & 3].u[d] = cload(ap1 + (kb + 4) * 16 + d);
                }
            }
            acc[0][0] = __builtin_amdgcn_mfma_f32_16x16x32_f16(fa0, b0, acc[0][0], 0, 0, 0);
            acc[0][1] = __builtin_amdgcn_mfma_f32_16x16x32_f16(fa0, b1, acc[0][1], 0, 0, 0);
            acc[0][2] = __builtin_amdgcn_mfma_f32_16x16x32_f16(fa0, b2, acc[0][2], 0, 0, 0);
            acc[0][3] = __builtin_amdgcn_mfma_f32_16x16x32_f16(fa0, b3, acc[0][3], 0, 0, 0);
            acc[1][0] = __builtin_amdgcn_mfma_f32_16x16x32_f16(fa1, b0, acc[1][0], 0, 0, 0);
            acc[1][1] = __builtin_amdgcn_mfma_f32_16x16x32_f16(fa1, b1, acc[1][1], 0, 0, 0);
            acc[1][2] = __builtin_amdgcn_mfma_f32_16x16x32_f16(fa1, b2, acc[1][2], 0, 0, 0);
            acc[1][3] = __builtin_amdgcn_mfma_f32_16x16x32_f16(fa1, b3, acc[1][3], 0, 0, 0);
            b0 = n0; b1 = n1; b2 = n2; b3 = n3;
        }

        // elementwise (all 4 gates lane-local) + packed coherent h store
#pragma unroll
        for (int i = 0; i < 2; ++i) {
#pragma unroll
            for (int r = 0; r < 4; ++r) {
                const int row = rows0 + i * 16 + quad * 4 + r;
                const int gi  = row * NH + u0 + l16;
                const float iv = acc[i][0][r] + bi;
                const float fv = acc[i][1][r] + bf;
                const float gv = acc[i][2][r] + bg;
                const float ov = acc[i][3][r] + bo;
                const float cprev = i ? cv1[r] : cv0[r];
                const float cn = sigm(fv) * cprev + sigm(iv) * tanhf_(gv);
                cglob[gi] = cn;                             // private, stays in L2
                const float hv = sigm(ov) * tanhf_(cn);
                const f16 hf = (f16)hv;
                uint32_t hb = (uint32_t)__builtin_bit_cast(unsigned short, hf);
                uint32_t ob = (uint32_t)__shfl_xor((int)hb, 1);
                if ((l16 & 1) == 0)                          // even lane stores packed pair
                    cstore((uint32_t*)(hout + row * NH + u0 + l16), hb | (ob << 16));
            }
        }

        if (stp0) {                                         // finish fold, write out col t-1
            dot0 += __shfl_xor(dot0, 16);
            dot0 += __shfl_xor(dot0, 32);
            dot1 += __shfl_xor(dot1, 16);
            dot1 += __shfl_xor(dot1, 32);
            if (quad == 0) {
                out[(rows0 + l16) * NSEQ + (t - 1)]      = dot0 + bfc127;
                out[(rows0 + 16 + l16) * NSEQ + (t - 1)] = dot1 + bfc127;
            }
        }

        if (t + 1 < NSEQ) {
            // ---- group barrier (rt-group of 64 blocks), fence-free ----
            asm volatile("s_waitcnt vmcnt(0)" ::: "memory");  // h stores at LIC
            __syncthreads();
            if (tid == 0) {
                __hip_atomic_fetch_add(mybar, 1u, __ATOMIC_RELAXED, __HIP_MEMORY_SCOPE_AGENT);
                const unsigned target = (unsigned)t * 64u;
                if (!dead) {
                    unsigned tries = 0;
                    while (__hip_atomic_load(mybar, __ATOMIC_RELAXED,
                                             __HIP_MEMORY_SCOPE_AGENT) < target) {
                        __builtin_amdgcn_s_sleep(2);
                        if (++tries > 4000000u) { dead = 1; break; }  // fail fast, no hang
                    }
                }
            }
            __syncthreads();
        }
    }
}

// out[:,95] = h_96 . W_fc[127,:] + b_fc[127]
__global__ __launch_bounds__(256)
void final_kernel(const f16* __restrict__ h96, const float* __restrict__ wfc_last,
                  const float* __restrict__ b_fc, float* __restrict__ out)
{
    __shared__ float dred[64][4];
    const int tid = threadIdx.x;
    const int row = blockIdx.x * 64 + (tid >> 2);
    const int q = tid & 3;
    const f16* hr = h96 + row * NH + q * 256;
    const float* wf = wfc_last + q * 256;
    float s = 0.f;
    for (int j = 0; j < 256; ++j) s += (float)hr[j] * wf[j];
    dred[tid >> 2][q] = s;
    __syncthreads();
    if (tid < 64)
        out[(blockIdx.x * 64 + tid) * NSEQ + 95] =
            dred[tid][0] + dred[tid][1] + dred[tid][2] + dred[tid][3] + b_fc[127];
}

extern "C" void kernel_launch(void* const* d_in, const int* in_sizes, int n_in,
                              void* d_out, int out_size, void* d_ws, size_t ws_size,
                              hipStream_t stream) {
    const float* xt     = (const float*)d_in[0];
    const float* hidden = (const float*)d_in[1];
    float*       cglob  = (float*)d_in[2];     // cell state updated IN PLACE (restored each launch)
    const float* W_ih   = (const float*)d_in[3];
    const float* W_hh   = (const float*)d_in[4];
    const float* b_ih   = (const float*)d_in[5];
    const float* b_hh   = (const float*)d_in[6];
    const float* W_fc   = (const float*)d_in[7];
    const float* b_fc   = (const float*)d_in[8];
    float* out = (float*)d_out;
    const float* wfc_last = W_fc + 127 * NH;   // row 127 of W_fc, f32

    // 11,682,304 B total — under the R1-proven 11,943,936 budget.
    char* ws = (char*)d_ws;
    f16*   weff     = (f16*)(ws);               // 4096*1024*2 = 8,388,608
    f16*   wih      = (f16*)(ws + 8388608);     // 4096*128*2  = 1,048,576
    f16*   xbuf     = (f16*)(ws + 9437184);     // 512*128*2   =   131,072
    f16*   h0       = (f16*)(ws + 9568256);     // 512*1024*2  = 1,048,576
    f16*   h1       = (f16*)(ws + 10616832);    // 512*1024*2  = 1,048,576
    float* bias_eff = (float*)(ws + 11665408);  // 4096*4      =    16,384
    unsigned* bar   = (unsigned*)(ws + 11681792); // 512 B: 4 group counters, 128B apart

    hipLaunchKernelGGL(prep1_kernel, dim3(256), dim3(256), 0, stream,
                       xt, hidden, W_ih, b_ih, b_hh, b_fc, wih, xbuf, h0, bias_eff, bar);
    hipLaunchKernelGGL(prep2_kernel, dim3(512), dim3(256), 0, stream,
                       wih, W_fc, W_hh, weff);
    hipLaunchKernelGGL(step0_kernel, dim3(256), dim3(256), 0, stream,
                       xbuf, h0, h1, wih, W_hh, b_ih, b_hh, cglob);

    // steps t=1..95 in one persistent kernel; out cols 0..94 via strip-0 fold
    hipLaunchKernelGGL(lstm_persist, dim3(256), dim3(256), 0, stream,
                       h0, h1, weff, bias_eff, cglob, wfc_last, b_fc, out, bar);

    // h_96 parity: t=95 wrote hout = h0
    hipLaunchKernelGGL(final_kernel, dim3(8), dim3(256), 0, stream,
                       h0, wfc_last, b_fc, out);
}

// Round 6
// 1249.217 us; speedup vs baseline: 2.6760x; 2.6760x over previous
//
#include <hip/hip_runtime.h>

typedef _Float16 f16;
typedef __attribute__((ext_vector_type(4))) _Float16 f16x4;
typedef __attribute__((ext_vector_type(8))) _Float16 f16x8;
typedef __attribute__((ext_vector_type(4))) float f32x4;

#define NB   512
#define NI   128
#define NH   1024
#define NG   4096
#define NSEQ 96

__device__ __forceinline__ float sigm(float x)  { return 1.0f / (1.0f + __expf(-x)); }
__device__ __forceinline__ float tanhf_(float x){ return 2.0f / (1.0f + __expf(-2.0f * x)) - 1.0f; }

// R16: R15 with the asm ordering fixed per guide rule #18.
// R14/R15 compile error root cause: "+v" TIED constraints on 128-bit uint4
// are unsupported ("tied indirect register inputs") -- not array indexing.
// Fix: no ties. Ordering = asm volatile s_waitcnt (volatile asms keep mutual
// order with the volatile load asms -> vmcnt FIFO count exact) followed by
// __builtin_amdgcn_sched_barrier(0) (stops MFMA/VALU hoisting past the wait,
// rule #18). Ring slots halved: chunk 16+k reuses slot k after consumption.
// Numerics identical to passing R13 (absmax 0.00195).
// R13 evidence basis: 34.8us/step, MfmaUtil 5%, stall = h reads through LIC
// (scalar dword atomics, depth-4 ring). This kernel: dwordx4 coherent loads,
// depth-16 counted-vmcnt ring (512B/lane in flight).

__global__ __launch_bounds__(256)
void prep1_kernel(const float* __restrict__ xt, const float* __restrict__ hidden,
                  const float* __restrict__ W_ih, const float* __restrict__ b_ih,
                  const float* __restrict__ b_hh, const float* __restrict__ b_fc,
                  f16* __restrict__ wih, f16* __restrict__ xbuf,
                  f16* __restrict__ h0, float* __restrict__ bias_eff,
                  unsigned* __restrict__ bar)
{
    const int gid = blockIdx.x * 256 + threadIdx.x;
    const int GSZ = 256 * 256;
    if (gid < 128) bar[gid] = 0u;         // 4 group counters (128B-spaced), re-zeroed every launch
    { const float4* s = (const float4*)W_ih; f16x4* d = (f16x4*)wih;
      for (int i = gid; i < NG * NI / 4; i += GSZ) { float4 v = s[i]; d[i] = f16x4{(f16)v.x,(f16)v.y,(f16)v.z,(f16)v.w}; } }
    { const float4* s = (const float4*)xt; f16x4* d = (f16x4*)xbuf;
      for (int i = gid; i < NB * NI / 4; i += GSZ) { float4 v = s[i]; d[i] = f16x4{(f16)v.x,(f16)v.y,(f16)v.z,(f16)v.w}; } }
    { const float4* s = (const float4*)hidden; f16x4* d = (f16x4*)h0;
      for (int i = gid; i < NB * NH / 4; i += GSZ) { float4 v = s[i]; d[i] = f16x4{(f16)v.x,(f16)v.y,(f16)v.z,(f16)v.w}; } }
    if (gid < NG) {                       // bias_eff[n] = b_ih+b_hh + W_ih[n,:].b_fc
        float s = b_ih[gid] + b_hh[gid];
        const float* wr = W_ih + gid * NI;
        for (int j = 0; j < NI; ++j) s += wr[j] * b_fc[j];
        bias_eff[gid] = s;
    }
}

// W_eff = W_hh + W_ih @ W_fc  -> fp16.  512 blocks: (nt=bid>>3)x(kt=bid&7),
// tile = 64 gate-rows x 128 k-cols, K=128.
__global__ __launch_bounds__(256)
void prep2_kernel(const f16* __restrict__ wih, const float* __restrict__ W_fc,
                  const float* __restrict__ W_hh, f16* __restrict__ weff)
{
    __shared__ f16 ldsW[64 * 136];        // A tile 64x128 fp16, pitch 136

    const int tid = threadIdx.x;
    const int nt = blockIdx.x >> 3, kt = blockIdx.x & 7;
    const int w = tid >> 6, lane = tid & 63, quad = lane >> 4, l16 = lane & 15;

    for (int s = 0; s < 4; ++s) {
        const int slot = tid + s * 256;            // 1024 vec8 slots
        const int row = slot >> 4, colv = slot & 15;
        *(f16x8*)(ldsW + row * 136 + colv * 8) =
            *(const f16x8*)(wih + (nt * 64 + row) * NI + colv * 8);
    }
    __syncthreads();

    f32x4 acc[4][2];
#pragma unroll
    for (int mt = 0; mt < 4; ++mt) { acc[mt][0] = f32x4{0,0,0,0}; acc[mt][1] = f32x4{0,0,0,0}; }

    const int nc0 = kt * 128 + w * 32;
#pragma unroll
    for (int c = 0; c < 4; ++c) {
        f16x8 bf0, bf1;
#pragma unroll
        for (int j = 0; j < 8; ++j) {
            const int krow = c * 32 + quad * 8 + j;
            bf0[j] = (f16)W_fc[krow * NH + nc0 + l16];
            bf1[j] = (f16)W_fc[krow * NH + nc0 + 16 + l16];
        }
#pragma unroll
        for (int mt = 0; mt < 4; ++mt) {
            f16x8 afr = *(const f16x8*)(ldsW + (mt * 16 + l16) * 136 + c * 32 + quad * 8);
            acc[mt][0] = __builtin_amdgcn_mfma_f32_16x16x32_f16(afr, bf0, acc[mt][0], 0, 0, 0);
            acc[mt][1] = __builtin_amdgcn_mfma_f32_16x16x32_f16(afr, bf1, acc[mt][1], 0, 0, 0);
        }
    }

#pragma unroll
    for (int mt = 0; mt < 4; ++mt)
#pragma unroll
        for (int r = 0; r < 4; ++r) {
            const int n = nt * 64 + mt * 16 + quad * 4 + r;
            weff[n * NH + nc0 + l16]      = (f16)(acc[mt][0][r] + W_hh[n * NH + nc0 + l16]);
            weff[n * NH + nc0 + 16 + l16] = (f16)(acc[mt][1][r] + W_hh[n * NH + nc0 + 16 + l16]);
        }
}

// t=0: gates = x0@W_ih^T + h0@W_hh^T + (b_ih+b_hh); K=1152. W_hh read f32.
__global__ __launch_bounds__(256)
void step0_kernel(const f16* __restrict__ xbuf, const f16* __restrict__ hin,
                  f16* __restrict__ hout, const f16* __restrict__ wih,
                  const float* __restrict__ W_hh, const float* __restrict__ b_ih,
                  const float* __restrict__ b_hh, float* __restrict__ cglob)
{
    __shared__ f16   ldsA[2 * 64 * 40];
    __shared__ float gbuf[4][64][33];

    const int tid = threadIdx.x, bid = blockIdx.x;
    const int r0 = (bid >> 5) * 64, u0 = (bid & 31) * 32;
    const int w = tid >> 6, lane = tid & 63, quad = lane >> 4, l16 = lane & 15;
    const int srow = tid >> 2, skk = (tid & 3) * 8;

    const int n0g = w * NH + u0 + l16;
    const f16*   wip0 = wih + n0g * NI + quad * 8;
    const f16*   wip1 = wip0 + 16 * NI;
    const float* whf0 = W_hh + n0g * NH + quad * 8;
    const float* whf1 = whf0 + 16 * NH;
    const float bias0 = b_ih[n0g]      + b_hh[n0g];
    const float bias1 = b_ih[n0g + 16] + b_hh[n0g + 16];

    const f16* xrow = xbuf + (r0 + srow) * NI + skk;
    const f16* hrow = hin  + (r0 + srow) * NH + skk;

    f32x4 acc[4][2];
#pragma unroll
    for (int mt = 0; mt < 4; ++mt) { acc[mt][0] = f32x4{0,0,0,0}; acc[mt][1] = f32x4{0,0,0,0}; }

    auto loadA = [&](int kb) -> f16x8 {
        const int k0 = kb * 32;
        if (k0 < NI) return *(const f16x8*)(xrow + k0);
        return *(const f16x8*)(hrow + (k0 - NI));
    };
    auto cvt8 = [&](const float* p) -> f16x8 {
        float4 a = *(const float4*)p, b = *(const float4*)(p + 4);
        return f16x8{(f16)a.x,(f16)a.y,(f16)a.z,(f16)a.w,(f16)b.x,(f16)b.y,(f16)b.z,(f16)b.w};
    };
    auto loadB0 = [&](int kb) -> f16x8 {
        const int k0 = kb * 32;
        if (k0 < NI) return *(const f16x8*)(wip0 + k0);
        return cvt8(whf0 + (k0 - NI));
    };
    auto loadB1 = [&](int kb) -> f16x8 {
        const int k0 = kb * 32;
        if (k0 < NI) return *(const f16x8*)(wip1 + k0);
        return cvt8(whf1 + (k0 - NI));
    };

    f16x8 av = loadA(0);
    *(f16x8*)(ldsA + srow * 40 + skk) = av;
    av = loadA(1);
    f16x8 b0 = loadB0(0), b1 = loadB1(0);

    for (int kb = 0; kb < 36; ++kb) {
        __syncthreads();
        if (kb + 1 < 36) {
            *(f16x8*)(ldsA + ((kb + 1) & 1) * 2560 + srow * 40 + skk) = av;
            av = loadA(kb + 2 < 36 ? kb + 2 : 35);
        }
        const int kn = (kb + 1 < 36) ? kb + 1 : 35;
        f16x8 nb0 = loadB0(kn), nb1 = loadB1(kn);
        const f16* abase = ldsA + (kb & 1) * 2560 + l16 * 40 + quad * 8;
#pragma unroll
        for (int mt = 0; mt < 4; ++mt) {
            f16x8 afr = *(const f16x8*)(abase + mt * 640);
            acc[mt][0] = __builtin_amdgcn_mfma_f32_16x16x32_f16(afr, b0, acc[mt][0], 0, 0, 0);
            acc[mt][1] = __builtin_amdgcn_mfma_f32_16x16x32_f16(afr, b1, acc[mt][1], 0, 0, 0);
        }
        b0 = nb0; b1 = nb1;
    }

#pragma unroll
    for (int mt = 0; mt < 4; ++mt)
#pragma unroll
        for (int r = 0; r < 4; ++r) {
            gbuf[w][mt * 16 + quad * 4 + r][l16]      = acc[mt][0][r] + bias0;
            gbuf[w][mt * 16 + quad * 4 + r][16 + l16] = acc[mt][1][r] + bias1;
        }
    __syncthreads();

    {
        const int uu = tid & 31, rbase = (tid >> 5) * 8;
#pragma unroll
        for (int s = 0; s < 8; ++s) {
            const int rr = rbase + s;
            const int gi = (r0 + rr) * NH + u0 + uu;
            const float iv = gbuf[0][rr][uu], fv = gbuf[1][rr][uu];
            const float gv = gbuf[2][rr][uu], ov = gbuf[3][rr][uu];
            const float cn = sigm(fv) * cglob[gi] + sigm(iv) * tanhf_(gv);
            cglob[gi] = cn;
            hout[gi]  = (f16)(sigm(ov) * tanhf_(cn));
        }
    }
}

// ---- R16 asm helpers for lstm_persist (no tied operands) ----
#define MFMA16(A, B, C) __builtin_amdgcn_mfma_f32_16x16x32_f16((A), (B), (C), 0, 0, 0)

#define ALP(SLOT, OFF) \
    asm volatile("global_load_dwordx4 %0, %1, %2 offset:" #OFF " sc0 sc1" \
                 : "=v"(a0_##SLOT) : "v"(voff0), "s"(hinp)); \
    asm volatile("global_load_dwordx4 %0, %1, %2 offset:" #OFF " sc0 sc1" \
                 : "=v"(a1_##SLOT) : "v"(voff1), "s"(hinp));

// Volatile waitcnt keeps order vs the volatile load asms (exact FIFO count);
// sched_barrier(0) right after stops MFMA/VALU hoisting past it (rule #18).
#define KWAIT(NW) \
    asm volatile("s_waitcnt vmcnt(" #NW ")" ::: "memory"); \
    __builtin_amdgcn_sched_barrier(0);

#define KCORE(KB) \
    { \
        const int kn_ = ((KB) + 1) & 31; \
        f16x8 n0 = lb[(0 * 32 + kn_) * 64 + lane]; \
        f16x8 n1 = lb[(1 * 32 + kn_) * 64 + lane]; \
        f16x8 n2 = lb[(2 * 32 + kn_) * 64 + lane]; \
        f16x8 n3 = lb[(3 * 32 + kn_) * 64 + lane]; \
        if (stp0) { \
            const float* wf = ldsWfc + (KB) * 32 + quad * 8; \
            _Pragma("unroll") \
            for (int j = 0; j < 8; ++j) { \
                dot0 += (float)fa0[j] * wf[j]; \
                dot1 += (float)fa1[j] * wf[j]; \
            } \
        } \
        acc[0][0] = MFMA16(fa0, b0, acc[0][0]); \
        acc[0][1] = MFMA16(fa0, b1, acc[0][1]); \
        acc[0][2] = MFMA16(fa0, b2, acc[0][2]); \
        acc[0][3] = MFMA16(fa0, b3, acc[0][3]); \
        acc[1][0] = MFMA16(fa1, b0, acc[1][0]); \
        acc[1][1] = MFMA16(fa1, b1, acc[1][1]); \
        acc[1][2] = MFMA16(fa1, b2, acc[1][2]); \
        acc[1][3] = MFMA16(fa1, b3, acc[1][3]); \
        b0 = n0; b1 = n1; b2 = n2; b3 = n3; \
    }

// consume chunk KB (in slot KB), then issue chunk 16+KB into the SAME slot
// (old value already copied out via fa0/fa1 -> WAR handled by regalloc)
#define KSTEPI(KB, OFF2) { \
    KWAIT(30) \
    const f16x8 fa0 = __builtin_bit_cast(f16x8, a0_##KB); \
    const f16x8 fa1 = __builtin_bit_cast(f16x8, a1_##KB); \
    ALP(KB, OFF2) \
    KCORE(KB) }

// consume chunk KB (held in slot SLOT = KB-16)
#define KSTEPN(KB, SLOT, NW) { \
    KWAIT(NW) \
    const f16x8 fa0 = __builtin_bit_cast(f16x8, a0_##SLOT); \
    const f16x8 fa1 = __builtin_bit_cast(f16x8, a1_##SLOT); \
    KCORE(KB) }

__device__ __forceinline__ void cstore(uint32_t* p, uint32_t v) {
    __hip_atomic_store(p, v, __ATOMIC_RELAXED, __HIP_MEMORY_SCOPE_AGENT);
}

// Persistent kernel: steps t=1..95.  256 blocks (1/CU) x 256 threads.
// block = (rt = bid>>6: 128-row tile) x (us = bid&63: 16-unit strip).
// W_eff strip in LDS (fragment order, 128 KiB, loaded once); c in registers
// for all 95 steps; h via coherent dwordx4 loads, depth-16 counted-vmcnt ring.
__global__ __launch_bounds__(256, 1)
void lstm_persist(f16* h0, f16* h1,
                  const f16* __restrict__ weff, const float* __restrict__ bias_eff,
                  const float* __restrict__ cglob, const float* __restrict__ wfc_last,
                  const float* __restrict__ b_fc, float* __restrict__ out,
                  unsigned* bar)
{
    __shared__ f16   ldsB[4 * 32 * 64 * 8];   // 128 KiB: frag[(g*32+kb)*64 + lane]
    __shared__ float ldsWfc[NH];              // 4 KiB: W_fc row 127 (strip-0 fold)

    const int tid = threadIdx.x, bid = blockIdx.x;
    const int rt = bid >> 6, us = bid & 63;
    const int u0 = us * 16;
    const int w = tid >> 6, lane = tid & 63, quad = lane >> 4, l16 = lane & 15;
    const bool stp0 = (us == 0);

    // ---- preload W strip into LDS in fragment order (wave w owns gate g=w) ----
    {
        const f16* src = weff + (w * NH + u0 + l16) * NH + quad * 8;
        f16x8* dst = ((f16x8*)ldsB) + (w * 32) * 64 + lane;
#pragma unroll
        for (int kb = 0; kb < 32; ++kb)
            dst[kb * 64] = *(const f16x8*)(src + kb * 32);
    }
    for (int i = tid; i < NH; i += 256) ldsWfc[i] = wfc_last[i];

    const float bi = bias_eff[0 * NH + u0 + l16];
    const float bf = bias_eff[1 * NH + u0 + l16];
    const float bg = bias_eff[2 * NH + u0 + l16];
    const float bo = bias_eff[3 * NH + u0 + l16];
    const float bfc127 = b_fc[127];

    const int rows0 = rt * 128 + w * 32;
    const int aoff0 = (rows0 + l16) * NH + quad * 8;        // f16 elems, 16B aligned
    const int aoff1 = aoff0 + 16 * NH;
    const int gbase = (rows0 + quad * 4) * NH + u0 + l16;   // + (i*16 + r)*NH

    const unsigned voff0 = (unsigned)(aoff0 * 2);           // byte offsets for asm loads
    const unsigned voff1 = (unsigned)(aoff1 * 2);

    // cell state in REGISTERS for all 95 steps (c1 from step0; never re-read)
    float cv0[4], cv1[4];
#pragma unroll
    for (int r = 0; r < 4; ++r) {
        cv0[r] = cglob[gbase + r * NH];
        cv1[r] = cglob[gbase + (16 + r) * NH];
    }
    // force bias/cv loads to complete before the barrier-synced loop (keeps
    // the K-loop's vmcnt accounting exact)
    asm volatile("" :: "v"(bi), "v"(bf), "v"(bg), "v"(bo), "v"(bfc127),
                       "v"(cv0[0]), "v"(cv0[1]), "v"(cv0[2]), "v"(cv0[3]),
                       "v"(cv1[0]), "v"(cv1[1]), "v"(cv1[2]), "v"(cv1[3]));

    unsigned* mybar = bar + rt * 32;        // 128B-spaced group counters
    const f16x8* lb = (const f16x8*)ldsB;

    int dead = 0;                           // barrier-timeout flag (thread 0 only)
    __syncthreads();                        // W strip + wfc ready (drains all vmem)

#pragma unroll 1
    for (int t = 1; t < NSEQ; ++t) {
        const f16* hin  = (t & 1) ? h1 : h0;
        f16*       hout = (t & 1) ? h0 : h1;
        const f16* hinp = hin;

        // 16 named ring slots per A-half (peak 32 live uint4 = 128 VGPRs)
        uint4 a0_0,  a0_1,  a0_2,  a0_3,  a0_4,  a0_5,  a0_6,  a0_7;
        uint4 a0_8,  a0_9,  a0_10, a0_11, a0_12, a0_13, a0_14, a0_15;
        uint4 a1_0,  a1_1,  a1_2,  a1_3,  a1_4,  a1_5,  a1_6,  a1_7;
        uint4 a1_8,  a1_9,  a1_10, a1_11, a1_12, a1_13, a1_14, a1_15;

        // prologue: issue chunks 0..15 (32 loads in flight)
        ALP(0, 0)     ALP(1, 64)    ALP(2, 128)   ALP(3, 192)
        ALP(4, 256)   ALP(5, 320)   ALP(6, 384)   ALP(7, 448)
        ALP(8, 512)   ALP(9, 576)   ALP(10, 640)  ALP(11, 704)
        ALP(12, 768)  ALP(13, 832)  ALP(14, 896)  ALP(15, 960)

        f16x8 b0 = lb[(0 * 32 + 0) * 64 + lane];
        f16x8 b1 = lb[(1 * 32 + 0) * 64 + lane];
        f16x8 b2 = lb[(2 * 32 + 0) * 64 + lane];
        f16x8 b3 = lb[(3 * 32 + 0) * 64 + lane];

        f32x4 acc[2][4];
#pragma unroll
        for (int i = 0; i < 2; ++i)
#pragma unroll
            for (int g = 0; g < 4; ++g) acc[i][g] = f32x4{0.f, 0.f, 0.f, 0.f};

        float dot0 = 0.f, dot1 = 0.f;       // strip-0 fold: out[:,t-1] = hin . wfc

        // K-loop. KSTEPI(KB): wait vmcnt(30) (chunk KB = oldest pair of 32),
        // consume, issue chunk 16+KB into slot KB.
        KSTEPI(0, 1024)  KSTEPI(1, 1088)  KSTEPI(2, 1152)  KSTEPI(3, 1216)
        KSTEPI(4, 1280)  KSTEPI(5, 1344)  KSTEPI(6, 1408)  KSTEPI(7, 1472)
        KSTEPI(8, 1536)  KSTEPI(9, 1600)  KSTEPI(10, 1664) KSTEPI(11, 1728)
        KSTEPI(12, 1792) KSTEPI(13, 1856) KSTEPI(14, 1920) KSTEPI(15, 1984)
        // KSTEPN(KB, slot=KB-16, NW=(31-KB)*2)
        KSTEPN(16, 0, 30)   KSTEPN(17, 1, 28)   KSTEPN(18, 2, 26)   KSTEPN(19, 3, 24)
        KSTEPN(20, 4, 22)   KSTEPN(21, 5, 20)   KSTEPN(22, 6, 18)   KSTEPN(23, 7, 16)
        KSTEPN(24, 8, 14)   KSTEPN(25, 9, 12)   KSTEPN(26, 10, 10)  KSTEPN(27, 11, 8)
        KSTEPN(28, 12, 6)   KSTEPN(29, 13, 4)   KSTEPN(30, 14, 2)   KSTEPN(31, 15, 0)

        // elementwise (all 4 gates lane-local, c in regs) + packed coherent h store
#pragma unroll
        for (int i = 0; i < 2; ++i) {
#pragma unroll
            for (int r = 0; r < 4; ++r) {
                const int row = rows0 + i * 16 + quad * 4 + r;
                const float iv = acc[i][0][r] + bi;
                const float fv = acc[i][1][r] + bf;
                const float gv = acc[i][2][r] + bg;
                const float ov = acc[i][3][r] + bo;
                const float cprev = i ? cv1[r] : cv0[r];
                const float cn = sigm(fv) * cprev + sigm(iv) * tanhf_(gv);
                if (i) cv1[r] = cn; else cv0[r] = cn;
                const float hv = sigm(ov) * tanhf_(cn);
                const f16 hf = (f16)hv;
                uint32_t hb = (uint32_t)__builtin_bit_cast(unsigned short, hf);
                uint32_t ob = (uint32_t)__shfl_xor((int)hb, 1);
                if ((l16 & 1) == 0)                          // even lane stores packed pair
                    cstore((uint32_t*)(hout + row * NH + u0 + l16), hb | (ob << 16));
            }
        }

        if (stp0) {                                         // finish fold, write out col t-1
            dot0 += __shfl_xor(dot0, 16);
            dot0 += __shfl_xor(dot0, 32);
            dot1 += __shfl_xor(dot1, 16);
            dot1 += __shfl_xor(dot1, 32);
            if (quad == 0) {
                out[(rows0 + l16) * NSEQ + (t - 1)]      = dot0 + bfc127;
                out[(rows0 + 16 + l16) * NSEQ + (t - 1)] = dot1 + bfc127;
            }
        }

        if (t + 1 < NSEQ) {
            // ---- group barrier (rt-group of 64 blocks), fence-free ----
            asm volatile("s_waitcnt vmcnt(0)" ::: "memory");  // h stores at LIC
            __syncthreads();
            if (tid == 0) {
                __hip_atomic_fetch_add(mybar, 1u, __ATOMIC_RELAXED, __HIP_MEMORY_SCOPE_AGENT);
                const unsigned target = (unsigned)t * 64u;
                if (!dead) {
                    unsigned tries = 0;
                    while (__hip_atomic_load(mybar, __ATOMIC_RELAXED,
                                             __HIP_MEMORY_SCOPE_AGENT) < target) {
                        __builtin_amdgcn_s_sleep(2);
                        if (++tries > 4000000u) { dead = 1; break; }  // fail fast, no hang
                    }
                }
            }
            __syncthreads();
        }
    }
}

// out[:,95] = h_96 . W_fc[127,:] + b_fc[127]
__global__ __launch_bounds__(256)
void final_kernel(const f16* __restrict__ h96, const float* __restrict__ wfc_last,
                  const float* __restrict__ b_fc, float* __restrict__ out)
{
    __shared__ float dred[64][4];
    const int tid = threadIdx.x;
    const int row = blockIdx.x * 64 + (tid >> 2);
    const int q = tid & 3;
    const f16* hr = h96 + row * NH + q * 256;
    const float* wf = wfc_last + q * 256;
    float s = 0.f;
    for (int j = 0; j < 256; ++j) s += (float)hr[j] * wf[j];
    dred[tid >> 2][q] = s;
    __syncthreads();
    if (tid < 64)
        out[(blockIdx.x * 64 + tid) * NSEQ + 95] =
            dred[tid][0] + dred[tid][1] + dred[tid][2] + dred[tid][3] + b_fc[127];
}

extern "C" void kernel_launch(void* const* d_in, const int* in_sizes, int n_in,
                              void* d_out, int out_size, void* d_ws, size_t ws_size,
                              hipStream_t stream) {
    const float* xt     = (const float*)d_in[0];
    const float* hidden = (const float*)d_in[1];
    float*       cglob  = (float*)d_in[2];     // c1 written by step0; read-only for persist
    const float* W_ih   = (const float*)d_in[3];
    const float* W_hh   = (const float*)d_in[4];
    const float* b_ih   = (const float*)d_in[5];
    const float* b_hh   = (const float*)d_in[6];
    const float* W_fc   = (const float*)d_in[7];
    const float* b_fc   = (const float*)d_in[8];
    float* out = (float*)d_out;
    const float* wfc_last = W_fc + 127 * NH;   // row 127 of W_fc, f32

    // 11,682,304 B total — under the R1-proven 11,943,936 budget.
    char* ws = (char*)d_ws;
    f16*   weff     = (f16*)(ws);               // 4096*1024*2 = 8,388,608
    f16*   wih      = (f16*)(ws + 8388608);     // 4096*128*2  = 1,048,576
    f16*   xbuf     = (f16*)(ws + 9437184);     // 512*128*2   =   131,072
    f16*   h0       = (f16*)(ws + 9568256);     // 512*1024*2  = 1,048,576
    f16*   h1       = (f16*)(ws + 10616832);    // 512*1024*2  = 1,048,576
    float* bias_eff = (float*)(ws + 11665408);  // 4096*4      =    16,384
    unsigned* bar   = (unsigned*)(ws + 11681792); // 512 B: 4 group counters, 128B apart

    hipLaunchKernelGGL(prep1_kernel, dim3(256), dim3(256), 0, stream,
                       xt, hidden, W_ih, b_ih, b_hh, b_fc, wih, xbuf, h0, bias_eff, bar);
    hipLaunchKernelGGL(prep2_kernel, dim3(512), dim3(256), 0, stream,
                       wih, W_fc, W_hh, weff);
    hipLaunchKernelGGL(step0_kernel, dim3(256), dim3(256), 0, stream,
                       xbuf, h0, h1, wih, W_hh, b_ih, b_hh, cglob);

    // steps t=1..95 in one persistent kernel; out cols 0..94 via strip-0 fold
    hipLaunchKernelGGL(lstm_persist, dim3(256), dim3(256), 0, stream,
                       h0, h1, weff, bias_eff, cglob, wfc_last, b_fc, out, bar);

    // h_96 parity: t=95 wrote hout = h0
    hipLaunchKernelGGL(final_kernel, dim3(8), dim3(256), 0, stream,
                       h0, wfc_last, b_fc, out);
}